// Round 10
// baseline (474.323 us; speedup 1.0000x reference)
//
#include <hip/hip_runtime.h>
#include <math.h>
#include <float.h>

#define N_ROWS 32768
#define EDIM 256
#define NE 8192
#define NTILES 64            // 8192 / 128 n-tiles -> partials per row
#define DELTA 1.6e-3f        // rescue margin: ~5.7 sigma of f16 gap error
#define RB 16                // rows per phase-B group (halves ET rescans vs 8)

typedef unsigned int uint32;
typedef unsigned long long uint64;
typedef __attribute__((ext_vector_type(8))) _Float16 f16x8;  // 8 f16 = 4 VGPRs
typedef __attribute__((ext_vector_type(4))) float f32x4;

// ---- workspace layout (bytes) ----
#define OFF_ZCAT    ((size_t)0)           // 32768 x 256 f16, quarter-swizzled = 16777216
#define OFF_ECAT    ((size_t)33554432)    //  8192 x 256 f16 (256*E), quarter-swizzled = 4194304
#define OFF_ET      ((size_t)37748736)    //  256 x 8192 f32 (E^T) = 8388608
#define OFF_EN      ((size_t)46268416)    //  8192 f
#define OFF_PV      ((size_t)46301184)    // 64 x 32768 f  (after merge: lossp @+0, rowlist @+32768)
#define OFF_PI      ((size_t)54689792)    // 64 x 32768 i
#define OFF_PV2     ((size_t)63078400)    // 64 x 32768 f  (after merge: cursor @+0, offs @+32768)
#define OFF_IDX     ((size_t)71467008)    // 32768 i
#define OFF_BINS    ((size_t)71598080)    //  8192 i (hist)
#define OFF_PACKED  ((size_t)71630848)    // 32768 u64 = 262144
#define OFF_FLAGCNT ((size_t)71892992)    // int (padded)
#define OFF_FLAGGED ((size_t)71893504)    // 32768 i

__device__ __forceinline__ uint32 pack2_f16(float a, float b) {
    _Float16 ha = (_Float16)a;   // v_cvt_f16_f32, RNE
    _Float16 hb = (_Float16)b;
    unsigned short ua = __builtin_bit_cast(unsigned short, ha);
    unsigned short ub = __builtin_bit_cast(unsigned short, hb);
    return (uint32)ua | ((uint32)ub << 16);
}

__device__ __forceinline__ void gload_lds16(const void* g, void* l) {
    __builtin_amdgcn_global_load_lds(
        (const __attribute__((address_space(1))) uint32*)g,
        (__attribute__((address_space(3))) uint32*)l, 16, 0, 0);
}

// numpy pairwise-sum emulation of sum(a*a) for n=256 (validated round 3)
__device__ __forceinline__ float np_pairwise_sumsq(const float* a) {
#pragma clang fp contract(off)
    float h0, h1;
    #pragma unroll 1
    for (int hb = 0; hb < 2; ++hb) {
        const float* p = a + hb * 128;
        float r0=p[0]*p[0], r1=p[1]*p[1], r2=p[2]*p[2], r3=p[3]*p[3],
              r4=p[4]*p[4], r5=p[5]*p[5], r6=p[6]*p[6], r7=p[7]*p[7];
        #pragma unroll 1
        for (int i = 8; i < 128; i += 8) {
            r0 += p[i+0]*p[i+0]; r1 += p[i+1]*p[i+1];
            r2 += p[i+2]*p[i+2]; r3 += p[i+3]*p[i+3];
            r4 += p[i+4]*p[i+4]; r5 += p[i+5]*p[i+5];
            r6 += p[i+6]*p[i+6]; r7 += p[i+7]*p[i+7];
        }
        float s = ((r0+r1)+(r2+r3))+((r4+r5)+(r6+r7));
        if (hb == 0) h0 = s; else h1 = s;
    }
    return h0 + h1;
}

// Fused prep + init: [0,4096) convert Z; [4096,5120) convert E (+ET via LDS
// transpose + enorm from the same LDS tile); [5120,5152) packed=~0;
// [5152,5184) hist=0 (+flagcnt).
__global__ void k_prep(const float* __restrict__ Z, const float* __restrict__ E,
                       unsigned short* __restrict__ Zcat, unsigned short* __restrict__ Ecat,
                       float* __restrict__ ET, float* __restrict__ en,
                       uint64* __restrict__ packed, int* __restrict__ hist,
                       int* __restrict__ flagcnt) {
    __shared__ float tile[8][264];   // [r8][k], padded row
    int b = blockIdx.x;
    int t = threadIdx.x;
    if (b < 4096) {
        // Zcat: per row 8 chunks of 32 k, each chunk 4 quarters of 8 f16.
        // Global slot (r,c,q) holds logical quarter q ^ s(r), s(r)=(r>>1)&3.
        int r = b * 8 + (t >> 5);
        int u = t & 31;
        int c = u >> 2, q = u & 3;
        int lq = q ^ ((r >> 1) & 3);
        int k0 = c * 32 + lq * 8;
        const float4* zp = (const float4*)(Z + (size_t)r * EDIM + k0);
        float4 a = zp[0], bb = zp[1];
        float f[8] = {a.x,a.y,a.z,a.w,bb.x,bb.y,bb.z,bb.w};
        uint32 o[4];
        #pragma unroll
        for (int j = 0; j < 4; ++j) o[j] = pack2_f16(f[2*j], f[2*j+1]);
        *(uint4*)(Zcat + (size_t)r * 256 + c * 32 + q * 8) = make_uint4(o[0],o[1],o[2],o[3]);
    } else if (b < 5120) {
        // Ecat: f16 of 256*E (scale dodges f16 denormals); same swizzle.
        // ET (f32, unscaled, exact) via LDS transpose; enorm (np-exact) from
        // the same tile (rows are in natural k order).
        int eb = b - 4096;
        int r8 = t >> 5;
        int r = eb * 8 + r8;
        int u = t & 31;
        int c = u >> 2, q = u & 3;
        int lq = q ^ ((r >> 1) & 3);
        int k0 = c * 32 + lq * 8;
        const float4* ep = (const float4*)(E + (size_t)r * EDIM + k0);
        float4 a = ep[0], bb = ep[1];
        float f[8] = {a.x,a.y,a.z,a.w,bb.x,bb.y,bb.z,bb.w};
        uint32 o[4];
        #pragma unroll
        for (int j = 0; j < 4; ++j) o[j] = pack2_f16(256.0f*f[2*j], 256.0f*f[2*j+1]);
        *(uint4*)(Ecat + (size_t)r * 256 + c * 32 + q * 8) = make_uint4(o[0],o[1],o[2],o[3]);
        *(float4*)&tile[r8][k0]     = make_float4(f[0], f[1], f[2], f[3]);
        *(float4*)&tile[r8][k0 + 4] = make_float4(f[4], f[5], f[6], f[7]);
        __syncthreads();
        float4 lo, hi;
        lo.x = tile[0][t]; lo.y = tile[1][t]; lo.z = tile[2][t]; lo.w = tile[3][t];
        hi.x = tile[4][t]; hi.y = tile[5][t]; hi.z = tile[6][t]; hi.w = tile[7][t];
        float* dst = ET + (size_t)t * NE + eb * 8;
        *(float4*)dst = lo;
        *(float4*)(dst + 4) = hi;
        if (t < 8) en[eb * 8 + t] = np_pairwise_sumsq(&tile[t][0]);
    } else if (b < 5152) {
        int i = (b - 5120) * 256 + t;
        #pragma unroll
        for (int j = 0; j < 4; ++j) packed[i + j*8192] = 0xFFFFFFFFFFFFFFFFull;
    } else {
        hist[(b - 5152) * 256 + t] = 0;
        if (b == 5152 && t == 0) *flagcnt = 0;
    }
}

__device__ __forceinline__ uint32 float_key(float v) {
    uint32 b = __float_as_uint(v);
    return (b & 0x80000000u) ? ~b : (b | 0x80000000u);   // monotone total order
}

// Phase A: f16 z . f16 (256 e) MFMA GEMM, K=256. Round-7 ping-pong structure
// (best measured; depth-2 counted-vmcnt variant regressed via occupancy loss,
// round 9). Score = en - (2/256)*dot. Epilogue: float-domain top-2 via
// pairwise min/max tree (exact 2nd-min identity; exact ties have gap 0 ->
// always DELTA-flagged -> phaseB fixes idx). Reduce buffer [frow][group]
// stride-129 uint4: zero bank conflicts (verified round 4).
__global__ __launch_bounds__(256, 4) void k_gemm(
    const unsigned short* __restrict__ Zcat, const unsigned short* __restrict__ Ecat,
    const float* __restrict__ enorm,
    float* __restrict__ pv, int* __restrict__ pi, float* __restrict__ pv2)
{
    __shared__ __align__(16) char UB[33024];   // staging (32KB) / reduce 16*129*16B
    __shared__ float ens[128];
    __shared__ float fv1[128]; __shared__ int fi1[128]; __shared__ float fv2[128];

    unsigned short* As0 = (unsigned short*)(UB);
    unsigned short* As1 = (unsigned short*)(UB + 8192);
    unsigned short* Bs0 = (unsigned short*)(UB + 16384);
    unsigned short* Bs1 = (unsigned short*)(UB + 24576);

    int t = threadIdx.x;
    int nt = blockIdx.x & 63, mt = blockIdx.x >> 6;   // n fastest: A-band L2 reuse
    int wid = t >> 6, lane = t & 63;
    int wmg = wid >> 1, wng = wid & 1;
    int wm = wmg * 64, wn = wng * 64;

    if (t < 128) ens[t] = enorm[nt*128 + t];

    // staging: wave wid fills LDS j-blocks {2w,2w+1}; lane -> row j*16+(lane>>2),
    // quarter lane&3 (matches global slot layout -> swizzled LDS image)
    int j0 = wid*2, j1 = j0 + 1;
    int r0 = j0*16 + (lane >> 2), r1 = j1*16 + (lane >> 2);
    int c8 = (lane & 3) * 8;
    const unsigned short* gA0 = Zcat + (size_t)(mt*128 + r0)*256 + c8;
    const unsigned short* gA1 = Zcat + (size_t)(mt*128 + r1)*256 + c8;
    const unsigned short* gB0 = Ecat + (size_t)(nt*128 + r0)*256 + c8;
    const unsigned short* gB1 = Ecat + (size_t)(nt*128 + r1)*256 + c8;
    unsigned short* lA0s0 = As0 + j0*512;  unsigned short* lA1s0 = As0 + j1*512;
    unsigned short* lA0s1 = As1 + j0*512;  unsigned short* lA1s1 = As1 + j1*512;
    unsigned short* lB0s0 = Bs0 + j0*512;  unsigned short* lB1s0 = Bs0 + j1*512;
    unsigned short* lB0s1 = Bs1 + j0*512;  unsigned short* lB1s1 = Bs1 + j1*512;

    f32x4 acc[4][4];
    #pragma unroll
    for (int i = 0; i < 4; ++i)
        #pragma unroll
        for (int j = 0; j < 4; ++j) acc[i][j] = (f32x4){0.f,0.f,0.f,0.f};

    // fragment read: row = frow(+16i), quarter q=lane>>4 -> LDS quarter q^s(frow)
    int frow = lane & 15, q = lane >> 4;
    int sw = (frow >> 1) & 3;
    const unsigned short* a0Base = As0 + (wm + frow)*32 + ((q ^ sw) * 8);
    const unsigned short* a1Base = As1 + (wm + frow)*32 + ((q ^ sw) * 8);
    const unsigned short* b0Base = Bs0 + (wn + frow)*32 + ((q ^ sw) * 8);
    const unsigned short* b1Base = Bs1 + (wn + frow)*32 + ((q ^ sw) * 8);

    // prologue: stage chunk 0 into ping
    gload_lds16(gA0, lA0s0);
    gload_lds16(gA1, lA1s0);
    gload_lds16(gB0, lB0s0);
    gload_lds16(gB1, lB1s0);
    __syncthreads();

    #pragma unroll 1
    for (int c = 0; c < 8; ++c) {
        int nxt = c + 1;
        if (nxt < 8) {                 // stage next chunk into the other buffer
            int aOff = nxt * 32;
            if (nxt & 1) {
                gload_lds16(gA0 + aOff, lA0s1);
                gload_lds16(gA1 + aOff, lA1s1);
                gload_lds16(gB0 + aOff, lB0s1);
                gload_lds16(gB1 + aOff, lB1s1);
            } else {
                gload_lds16(gA0 + aOff, lA0s0);
                gload_lds16(gA1 + aOff, lA1s0);
                gload_lds16(gB0 + aOff, lB0s0);
                gload_lds16(gB1 + aOff, lB1s0);
            }
        }
        const unsigned short* aB = (c & 1) ? a1Base : a0Base;
        const unsigned short* bB = (c & 1) ? b1Base : b0Base;
        f16x8 af[4], bfr[4];
        #pragma unroll
        for (int i = 0; i < 4; ++i) bfr[i] = *(const f16x8*)(bB + i*16*32);
        #pragma unroll
        for (int i = 0; i < 4; ++i) af[i] = *(const f16x8*)(aB + i*16*32);
        #pragma unroll
        for (int i = 0; i < 4; ++i)
            #pragma unroll
            for (int j = 0; j < 4; ++j)
                acc[i][j] = __builtin_amdgcn_mfma_f32_16x16x32_f16(af[i], bfr[j], acc[i][j], 0, 0, 0);
        __syncthreads();   // drains this phase's loads AFTER the MFMA cluster
    }

    // ---- epilogue: D layout n = lane&15 (frow), m = q*4 + reg (+16i) ----
    // Two passes (i in {0,1} then {2,3}); reduce buffer aliases staging LDS.
    float ensr[4]; int nn[4];
    #pragma unroll
    for (int j = 0; j < 4; ++j) {
        int nl = wn + j*16 + frow;
        nn[j] = nt*128 + nl;
        ensr[j] = ens[nl];
    }
    uint4* P = (uint4*)UB;                 // [16][129] uint4
    int gbase = wng*64 + wmg*32 + q*4;     // + i2*16 + r per store

    #pragma unroll
    for (int ih = 0; ih < 2; ++ih) {
        // phase 1: local top-2 over j columns (pairwise tree, exact 2nd-min),
        // scatter (v1,i1,v2) to P[frow][g]
        #pragma unroll
        for (int i2 = 0; i2 < 2; ++i2) {
            int i = ih*2 + i2;
            #pragma unroll
            for (int r = 0; r < 4; ++r) {
                float s0 = fmaf(-0.0078125f, acc[i][0][r], ensr[0]);  // 2/256 e-unscale
                float s1 = fmaf(-0.0078125f, acc[i][1][r], ensr[1]);
                float s2 = fmaf(-0.0078125f, acc[i][2][r], ensr[2]);
                float s3 = fmaf(-0.0078125f, acc[i][3][r], ensr[3]);
                float a01 = fminf(s0, s1), b01 = fmaxf(s0, s1);
                float c23 = fminf(s2, s3), d23 = fmaxf(s2, s3);
                float v1 = fminf(a01, c23);
                float v2 = fminf(fminf(fmaxf(a01, c23), b01), d23);   // v_min3
                int iA = s1 < s0 ? nn[1] : nn[0];
                int iB = s3 < s2 ? nn[3] : nn[2];
                int i1 = c23 < a01 ? iB : iA;
                P[frow*129 + gbase + i2*16 + r] =
                    make_uint4(__float_as_uint(v1), (uint32)i1, __float_as_uint(v2), 0u);
            }
        }
        __syncthreads();
        // phase 2: 128 threads, one (col-half, row) each: merge 16 frow
        // partials as 4 parallel chains of 4 + tree (dep chain 15 -> 5)
        if (t < 128) {
            const uint4* base = P + t;
            float v1c[4], v2c[4]; int i1c[4];
            #pragma unroll
            for (int c4 = 0; c4 < 4; ++c4) {
                uint4 e0 = base[(c4*4)*129];
                float v1 = __uint_as_float(e0.x); int i1 = (int)e0.y;
                float v2 = __uint_as_float(e0.z);
                #pragma unroll
                for (int f = 1; f < 4; ++f) {
                    uint4 e = base[(c4*4 + f)*129];
                    float ov1 = __uint_as_float(e.x), ov2 = __uint_as_float(e.z);
                    v2 = fminf(fminf(v2, ov2), fmaxf(v1, ov1));
                    if (ov1 < v1) i1 = (int)e.y;
                    v1 = fminf(v1, ov1);
                }
                v1c[c4] = v1; i1c[c4] = i1; v2c[c4] = v2;
            }
            // tree: (0,2), (1,3), then (0,1)
            v2c[0] = fminf(fminf(v2c[0], v2c[2]), fmaxf(v1c[0], v1c[2]));
            if (v1c[2] < v1c[0]) i1c[0] = i1c[2];
            v1c[0] = fminf(v1c[0], v1c[2]);
            v2c[1] = fminf(fminf(v2c[1], v2c[3]), fmaxf(v1c[1], v1c[3]));
            if (v1c[3] < v1c[1]) i1c[1] = i1c[3];
            v1c[1] = fminf(v1c[1], v1c[3]);
            v2c[0] = fminf(fminf(v2c[0], v2c[1]), fmaxf(v1c[0], v1c[1]));
            if (v1c[1] < v1c[0]) i1c[0] = i1c[1];
            v1c[0] = fminf(v1c[0], v1c[1]);
            fv1[t] = v1c[0]; fi1[t] = i1c[0]; fv2[t] = v2c[0];
        }
        __syncthreads();
        // final: merge the two col-halves, write partials
        if (t < 64) {
            float v1 = fv1[t], v2 = fv2[t]; int i1 = fi1[t];
            float ov1 = fv1[64+t], ov2 = fv2[64+t];
            v2 = fminf(fminf(v2, ov2), fmaxf(v1, ov1));
            if (ov1 < v1) i1 = fi1[64+t];
            v1 = fminf(v1, ov1);
            size_t o = (size_t)nt * N_ROWS + mt*128 + (t>>5)*64 + ih*32 + (t&31);
            pv[o] = v1; pi[o] = i1; pv2[o] = v2;
        }
        // ih=1 phase-1 P-writes are safe: all P-reads completed before the
        // post-phase-2 barrier; fv*-reads above touch disjoint memory.
    }
}

// merge 64 n-tile partials per row; flag rows with gap < DELTA for np-exact rescan
__global__ void k_merge(const float* __restrict__ pv, const int* __restrict__ pi,
                        const float* __restrict__ pv2,
                        float* __restrict__ out_idx_f, int* __restrict__ idxint,
                        int* __restrict__ flagcnt, int* __restrict__ flagged) {
    int g = blockIdx.x * 256 + threadIdx.x;
    float B1 = FLT_MAX, B2 = FLT_MAX; int I1 = 0;
    #pragma unroll 1
    for (int p = 0; p < NTILES; ++p) {   // ascending p == ascending k
        size_t o = (size_t)p * N_ROWS + g;
        float v1 = pv[o], v2 = pv2[o]; int i1 = pi[o];
        if (v1 < B1) { B2 = fminf(B1, v2); B1 = v1; I1 = i1; }
        else B2 = fminf(B2, v1);
    }
    out_idx_f[g] = (float)I1;
    idxint[g] = I1;
    if (B2 - B1 < DELTA) {
        int slot = atomicAdd(flagcnt, 1);
        flagged[slot] = g;
    }
}

// Phase B: np-exact fp32 rescan (validated round-3 semantics). Task =
// (k-slice of 1024, group of RB flagged rows); zn computed in-kernel (np order);
// result via atomicMin on order-packed (score,idx).
__global__ void k_phaseB(const float* __restrict__ Z, const float* __restrict__ ET,
                         const float* __restrict__ enorm,
                         const int* __restrict__ flagcnt, const int* __restrict__ flagged,
                         uint64* __restrict__ packed) {
    __shared__ float zl[RB][256];
    __shared__ float znl[RB];
    __shared__ int rows[RB];
    __shared__ float sv[256]; __shared__ int si[256];
    int t = threadIdx.x;
    int cnt = *flagcnt; if (cnt > N_ROWS) cnt = N_ROWS;
    int ngrp = (cnt + RB - 1) / RB;
    int ntask = ngrp * 8;
    #pragma unroll 1
    for (int task = blockIdx.x; task < ntask; task += gridDim.x) {
        int slice = task & 7;
        int g0 = (task >> 3) * RB;
        __syncthreads();
        if (t < RB) {
            int f = g0 + t;
            rows[t] = flagged[f < cnt ? f : g0];   // clamp dup: recompute harmless
        }
        __syncthreads();
        #pragma unroll
        for (int rr = 0; rr < RB; ++rr) zl[rr][t] = Z[(size_t)rows[rr]*EDIM + t];
        __syncthreads();
        if (t < RB) znl[t] = np_pairwise_sumsq(&zl[t][0]);
        __syncthreads();

        float acc[RB][4];
        #pragma unroll
        for (int rr = 0; rr < RB; ++rr)
            #pragma unroll
            for (int c = 0; c < 4; ++c) acc[rr][c] = 0.f;
        const float* eb = ET + slice*1024 + t;
        #pragma unroll 1
        for (int d = 0; d < 256; ++d) {           // sequential ascending d (np order)
            const float* ep = eb + (size_t)d * NE;
            float v0 = ep[0], v1 = ep[256], v2 = ep[512], v3 = ep[768];
            #pragma unroll
            for (int rr = 0; rr < RB; ++rr) {
                float zd = zl[rr][d];
                acc[rr][0] = fmaf(zd, v0, acc[rr][0]);
                acc[rr][1] = fmaf(zd, v1, acc[rr][1]);
                acc[rr][2] = fmaf(zd, v2, acc[rr][2]);
                acc[rr][3] = fmaf(zd, v3, acc[rr][3]);
            }
        }
        #pragma unroll 1
        for (int rr = 0; rr < RB; ++rr) {
            int row = rows[rr];
            float zn = znl[rr];
            float bv = FLT_MAX; int bi = 0x7fffffff;
            {
#pragma clang fp contract(off)
                #pragma unroll
                for (int c = 0; c < 4; ++c) {
                    int k = slice*1024 + c*256 + t;
                    float S  = zn + enorm[k];
                    float tw = 2.0f * acc[rr][c];
                    float sc = S - tw;
                    if (sc < bv || (sc == bv && k < bi)) { bv = sc; bi = k; }
                }
            }
            sv[t] = bv; si[t] = bi;
            __syncthreads();
            for (int st = 128; st > 0; st >>= 1) {
                if (t < st) {
                    float ov = sv[t+st]; int oi = si[t+st];
                    if (ov < sv[t] || (ov == sv[t] && oi < si[t])) { sv[t] = ov; si[t] = oi; }
                }
                __syncthreads();
            }
            if (t == 0) {
                uint64 pk = ((uint64)float_key(sv[0]) << 32) | (uint32)si[0];
                atomicMin(packed + row, pk);
            }
            __syncthreads();
        }
    }
}

// tail A: apply phase-B idx fix, write z_q_st + loss partial, histogram idx.
__global__ void k_taila(const float* __restrict__ Z, const float* __restrict__ E,
                        int* __restrict__ idxint, const uint64* __restrict__ packed,
                        float* __restrict__ out0, float* __restrict__ out_idx_f,
                        int* __restrict__ hist, float* __restrict__ lossp) {
    __shared__ float wsum[4];
    int t = threadIdx.x;
    int w = t >> 6, lane = t & 63;
    int row = blockIdx.x * 4 + w;
    int idx = idxint[row];
    uint64 pk = packed[row];
    if (pk != 0xFFFFFFFFFFFFFFFFull) {          // flagged: exact rescan result
        idx = (int)(uint32)(pk & 0xffffffffu);
        if (lane == 0) { out_idx_f[row] = (float)idx; idxint[row] = idx; }
    }
    float4 z4 = ((const float4*)Z)[(size_t)row * 64 + lane];
    float4 e4 = ((const float4*)E)[(size_t)idx * 64 + lane];
    float4 d4; d4.x = e4.x - z4.x; d4.y = e4.y - z4.y; d4.z = e4.z - z4.z; d4.w = e4.w - z4.w;
    float4 o;  o.x = z4.x + d4.x;  o.y = z4.y + d4.y;  o.z = z4.z + d4.z;  o.w = z4.w + d4.w;
    ((float4*)out0)[(size_t)row * 64 + lane] = o;
    float q2 = d4.x*d4.x + d4.y*d4.y + d4.z*d4.z + d4.w*d4.w;
    #pragma unroll
    for (int off = 32; off > 0; off >>= 1) q2 += __shfl_down(q2, off, 64);
    if (lane == 0) { wsum[w] = q2; atomicAdd(&hist[idx], 1); }
    __syncthreads();
    if (t == 0) lossp[blockIdx.x] = wsum[0] + wsum[1] + wsum[2] + wsum[3];
}

// exclusive prefix-scan of hist[8192] -> offs and cursor (one block)
__global__ void k_scan(const int* __restrict__ hist,
                       int* __restrict__ cursor, int* __restrict__ offs) {
    __shared__ int part[256];
    int t = threadIdx.x;
    int loc[32];
    int s = 0;
    #pragma unroll
    for (int j = 0; j < 32; ++j) { loc[j] = s; s += hist[t*32 + j]; }
    part[t] = s;
    __syncthreads();
    // Hillis-Steele inclusive scan over 256 partials
    #pragma unroll
    for (int off = 1; off < 256; off <<= 1) {
        int u = (t >= off) ? part[t - off] : 0;
        __syncthreads();
        part[t] += u;
        __syncthreads();
    }
    int base = part[t] - s;   // exclusive base for this thread's 32 codes
    #pragma unroll
    for (int j = 0; j < 32; ++j) {
        int o = base + loc[j];
        offs[t*32 + j] = o;
        cursor[t*32 + j] = o;
    }
}

// tail B: scatter row ids into per-code segments
__global__ void k_tailb(const int* __restrict__ idxint,
                        int* __restrict__ cursor, int* __restrict__ rowlist) {
    int g = blockIdx.x * 256 + threadIdx.x;
    int idx = idxint[g];
    int pos = atomicAdd(&cursor[idx], 1);
    rowlist[pos] = g;
}

// dw gather-sum per code + cl divide + loss reduce (block 0)
__global__ void k_dw(const float* __restrict__ Z, const int* __restrict__ hist,
                     const int* __restrict__ offs, const int* __restrict__ rowlist,
                     const float* __restrict__ lossp,
                     float* __restrict__ out3, float* __restrict__ out2) {
    __shared__ double red[256];
    int k = blockIdx.x;
    int t = threadIdx.x;
    int cnt = hist[k];
    int start = offs[k];
    float s0 = 0.f, s1 = 0.f;
    int j = 0;
    #pragma unroll 1
    for (; j + 1 < cnt; j += 2) {
        int ra = rowlist[start + j];
        int rb = rowlist[start + j + 1];
        s0 += Z[(size_t)ra * EDIM + t];
        s1 += Z[(size_t)rb * EDIM + t];
    }
    if (j < cnt) s0 += Z[(size_t)rowlist[start + j] * EDIM + t];
    float sum = s0 + s1;
    float cl = ((float)cnt + 1e-5f) / (32768.0f + 8192.0f * 1e-5f) * 32768.0f;
    out3[(size_t)k * EDIM + t] = sum / cl;
    if (k == 0) {
        double s = 0.0;
        #pragma unroll 1
        for (int p = t; p < 8192; p += 256) s += (double)lossp[p];
        red[t] = s;
        __syncthreads();
        #pragma unroll
        for (int st = 128; st > 0; st >>= 1) {
            if (t < st) red[t] += red[t + st];
            __syncthreads();
        }
        if (t == 0) out2[0] = 0.25f * (float)(red[0] / 8388608.0);
    }
}

extern "C" void kernel_launch(void* const* d_in, const int* in_sizes, int n_in,
                              void* d_out, int out_size, void* d_ws, size_t ws_size,
                              hipStream_t stream) {
    const float* Z = (const float*)d_in[0];   // [32768, 256]
    const float* E = (const float*)d_in[1];   // [8192, 256]
    float* out  = (float*)d_out;
    float* out0 = out;                         // z_q_st  (8388608)
    float* out1 = out + 8388608;               // idx as float (32768)
    float* out2 = out1 + 32768;                // loss (1)
    float* out3 = out2 + 1;                    // new_embeddings (2097152)

    char* ws = (char*)d_ws;
    unsigned short* Zcat = (unsigned short*)(ws + OFF_ZCAT);
    unsigned short* Ecat = (unsigned short*)(ws + OFF_ECAT);
    float*  ET      = (float*)(ws + OFF_ET);
    float*  enorm   = (float*)(ws + OFF_EN);
    float*  pv      = (float*)(ws + OFF_PV);
    int*    pi      = (int*)  (ws + OFF_PI);
    float*  pv2     = (float*)(ws + OFF_PV2);
    int*    idxint  = (int*)  (ws + OFF_IDX);
    int*    hist    = (int*)  (ws + OFF_BINS);
    uint64* packed  = (uint64*)(ws + OFF_PACKED);
    int*    flagcnt = (int*)  (ws + OFF_FLAGCNT);
    int*    flagged = (int*)  (ws + OFF_FLAGGED);
    float*  lossp   = (float*)(ws + OFF_PV);                 // after merge
    int*    rowlist = (int*)  (ws + OFF_PV + 32768);         // after merge
    int*    cursor  = (int*)  (ws + OFF_PV2);                // after merge
    int*    offs    = (int*)  (ws + OFF_PV2 + 32768);        // after merge

    k_prep   <<<5184,         256, 0, stream>>>(Z, E, Zcat, Ecat, ET, enorm,
                                                packed, hist, flagcnt);
    k_gemm   <<<256 * NTILES, 256, 0, stream>>>(Zcat, Ecat, enorm, pv, pi, pv2);
    k_merge  <<<N_ROWS / 256, 256, 0, stream>>>(pv, pi, pv2, out1, idxint, flagcnt, flagged);
    k_phaseB <<<2048,         256, 0, stream>>>(Z, ET, enorm, flagcnt, flagged, packed);
    k_taila  <<<N_ROWS / 4,   256, 0, stream>>>(Z, E, idxint, packed, out0, out1, hist, lossp);
    k_scan   <<<1,            256, 0, stream>>>(hist, cursor, offs);
    k_tailb  <<<N_ROWS / 256, 256, 0, stream>>>(idxint, cursor, rowlist);
    k_dw     <<<NE,           256, 0, stream>>>(Z, hist, offs, rowlist, lossp, out3, out2);
}

// Round 11
// 429.765 us; speedup vs baseline: 1.1037x; 1.1037x over previous
//
#include <hip/hip_runtime.h>
#include <math.h>
#include <float.h>

#define N_ROWS 32768
#define EDIM 256
#define NE 8192
#define NTILES 64            // 8192 / 128 n-tiles -> partials per row
#define DELTA 1.6e-3f        // rescue margin: ~5.7 sigma of f16 gap error
#define RB 8                 // rows per phase-B group (16 regressed: phaseB is parallelism-bound, round 10)

typedef unsigned int uint32;
typedef unsigned long long uint64;
typedef __attribute__((ext_vector_type(8))) _Float16 f16x8;  // 8 f16 = 4 VGPRs
typedef __attribute__((ext_vector_type(4))) float f32x4;

// ---- workspace layout (bytes) ----
#define OFF_ZCAT    ((size_t)0)           // 32768 x 256 f16, quarter-swizzled = 16777216
#define OFF_ECAT    ((size_t)33554432)    //  8192 x 256 f16 (256*E), quarter-swizzled = 4194304
#define OFF_ET      ((size_t)37748736)    //  256 x 8192 f32 (E^T) = 8388608
#define OFF_EN      ((size_t)46268416)    //  8192 f
#define OFF_PV      ((size_t)46301184)    // 64 x 32768 f  (after merge: lossp @+0, rowlist @+32768)
#define OFF_PI      ((size_t)54689792)    // 64 x 32768 i
#define OFF_PV2     ((size_t)63078400)    // 64 x 32768 f  (after merge: cursor @+0, offs @+32768)
#define OFF_IDX     ((size_t)71467008)    // 32768 i
#define OFF_BINS    ((size_t)71598080)    //  8192 i (hist)
#define OFF_PACKED  ((size_t)71630848)    // 32768 u64 = 262144
#define OFF_FLAGCNT ((size_t)71892992)    // int (padded)
#define OFF_FLAGGED ((size_t)71893504)    // 32768 i

__device__ __forceinline__ uint32 pack2_f16(float a, float b) {
    _Float16 ha = (_Float16)a;   // v_cvt_f16_f32, RNE
    _Float16 hb = (_Float16)b;
    unsigned short ua = __builtin_bit_cast(unsigned short, ha);
    unsigned short ub = __builtin_bit_cast(unsigned short, hb);
    return (uint32)ua | ((uint32)ub << 16);
}

__device__ __forceinline__ void gload_lds16(const void* g, void* l) {
    __builtin_amdgcn_global_load_lds(
        (const __attribute__((address_space(1))) uint32*)g,
        (__attribute__((address_space(3))) uint32*)l, 16, 0, 0);
}

// numpy pairwise-sum emulation of sum(a*a) for n=256 (validated round 3)
__device__ __forceinline__ float np_pairwise_sumsq(const float* a) {
#pragma clang fp contract(off)
    float h0, h1;
    #pragma unroll 1
    for (int hb = 0; hb < 2; ++hb) {
        const float* p = a + hb * 128;
        float r0=p[0]*p[0], r1=p[1]*p[1], r2=p[2]*p[2], r3=p[3]*p[3],
              r4=p[4]*p[4], r5=p[5]*p[5], r6=p[6]*p[6], r7=p[7]*p[7];
        #pragma unroll 1
        for (int i = 8; i < 128; i += 8) {
            r0 += p[i+0]*p[i+0]; r1 += p[i+1]*p[i+1];
            r2 += p[i+2]*p[i+2]; r3 += p[i+3]*p[i+3];
            r4 += p[i+4]*p[i+4]; r5 += p[i+5]*p[i+5];
            r6 += p[i+6]*p[i+6]; r7 += p[i+7]*p[i+7];
        }
        float s = ((r0+r1)+(r2+r3))+((r4+r5)+(r6+r7));
        if (hb == 0) h0 = s; else h1 = s;
    }
    return h0 + h1;
}

// Fused prep + init: [0,4096) convert Z; [4096,5120) convert E (+ET via LDS
// transpose + enorm from the same LDS tile); [5120,5152) packed=~0;
// [5152,5184) hist=0 (+flagcnt).
__global__ void k_prep(const float* __restrict__ Z, const float* __restrict__ E,
                       unsigned short* __restrict__ Zcat, unsigned short* __restrict__ Ecat,
                       float* __restrict__ ET, float* __restrict__ en,
                       uint64* __restrict__ packed, int* __restrict__ hist,
                       int* __restrict__ flagcnt) {
    __shared__ float tile[8][264];   // [r8][k], padded row
    int b = blockIdx.x;
    int t = threadIdx.x;
    if (b < 4096) {
        // Zcat: per row 8 chunks of 32 k, each chunk 4 quarters of 8 f16.
        // Global slot (r,c,q) holds logical quarter q ^ s(r), s(r)=(r>>1)&3.
        int r = b * 8 + (t >> 5);
        int u = t & 31;
        int c = u >> 2, q = u & 3;
        int lq = q ^ ((r >> 1) & 3);
        int k0 = c * 32 + lq * 8;
        const float4* zp = (const float4*)(Z + (size_t)r * EDIM + k0);
        float4 a = zp[0], bb = zp[1];
        float f[8] = {a.x,a.y,a.z,a.w,bb.x,bb.y,bb.z,bb.w};
        uint32 o[4];
        #pragma unroll
        for (int j = 0; j < 4; ++j) o[j] = pack2_f16(f[2*j], f[2*j+1]);
        *(uint4*)(Zcat + (size_t)r * 256 + c * 32 + q * 8) = make_uint4(o[0],o[1],o[2],o[3]);
    } else if (b < 5120) {
        // Ecat: f16 of 256*E (scale dodges f16 denormals); same swizzle.
        // ET (f32, unscaled, exact) via LDS transpose; enorm (np-exact) from
        // the same tile (rows are in natural k order).
        int eb = b - 4096;
        int r8 = t >> 5;
        int r = eb * 8 + r8;
        int u = t & 31;
        int c = u >> 2, q = u & 3;
        int lq = q ^ ((r >> 1) & 3);
        int k0 = c * 32 + lq * 8;
        const float4* ep = (const float4*)(E + (size_t)r * EDIM + k0);
        float4 a = ep[0], bb = ep[1];
        float f[8] = {a.x,a.y,a.z,a.w,bb.x,bb.y,bb.z,bb.w};
        uint32 o[4];
        #pragma unroll
        for (int j = 0; j < 4; ++j) o[j] = pack2_f16(256.0f*f[2*j], 256.0f*f[2*j+1]);
        *(uint4*)(Ecat + (size_t)r * 256 + c * 32 + q * 8) = make_uint4(o[0],o[1],o[2],o[3]);
        *(float4*)&tile[r8][k0]     = make_float4(f[0], f[1], f[2], f[3]);
        *(float4*)&tile[r8][k0 + 4] = make_float4(f[4], f[5], f[6], f[7]);
        __syncthreads();
        float4 lo, hi;
        lo.x = tile[0][t]; lo.y = tile[1][t]; lo.z = tile[2][t]; lo.w = tile[3][t];
        hi.x = tile[4][t]; hi.y = tile[5][t]; hi.z = tile[6][t]; hi.w = tile[7][t];
        float* dst = ET + (size_t)t * NE + eb * 8;
        *(float4*)dst = lo;
        *(float4*)(dst + 4) = hi;
        if (t < 8) en[eb * 8 + t] = np_pairwise_sumsq(&tile[t][0]);
    } else if (b < 5152) {
        int i = (b - 5120) * 256 + t;
        #pragma unroll
        for (int j = 0; j < 4; ++j) packed[i + j*8192] = 0xFFFFFFFFFFFFFFFFull;
    } else {
        hist[(b - 5152) * 256 + t] = 0;
        if (b == 5152 && t == 0) *flagcnt = 0;
    }
}

__device__ __forceinline__ uint32 float_key(float v) {
    uint32 b = __float_as_uint(v);
    return (b & 0x80000000u) ? ~b : (b | 0x80000000u);   // monotone total order
}

// Phase A: f16 z . f16 (256 e) MFMA GEMM, K=256. Round-7 ping-pong structure
// (best measured: 188.6us, 0 conflicts; depth-2 counted-vmcnt regressed via
// occupancy loss (r9); epilogue tree regressed via LDS conflicts (r10)).
// Score = en - (2/256)*dot. Epilogue: float-domain top-2, serial chains
// (exact ties have gap 0 -> always DELTA-flagged -> phaseB fixes idx).
// Reduce buffer [frow][group] stride-129 uint4: zero bank conflicts (r4).
__global__ __launch_bounds__(256, 4) void k_gemm(
    const unsigned short* __restrict__ Zcat, const unsigned short* __restrict__ Ecat,
    const float* __restrict__ enorm,
    float* __restrict__ pv, int* __restrict__ pi, float* __restrict__ pv2)
{
    __shared__ __align__(16) char UB[33024];   // staging (32KB) / reduce 16*129*16B
    __shared__ float ens[128];
    __shared__ float fv1[128]; __shared__ int fi1[128]; __shared__ float fv2[128];

    unsigned short* As0 = (unsigned short*)(UB);
    unsigned short* As1 = (unsigned short*)(UB + 8192);
    unsigned short* Bs0 = (unsigned short*)(UB + 16384);
    unsigned short* Bs1 = (unsigned short*)(UB + 24576);

    int t = threadIdx.x;
    int nt = blockIdx.x & 63, mt = blockIdx.x >> 6;   // n fastest: A-band L2 reuse
    int wid = t >> 6, lane = t & 63;
    int wmg = wid >> 1, wng = wid & 1;
    int wm = wmg * 64, wn = wng * 64;

    if (t < 128) ens[t] = enorm[nt*128 + t];

    // staging: wave wid fills LDS j-blocks {2w,2w+1}; lane -> row j*16+(lane>>2),
    // quarter lane&3 (matches global slot layout -> swizzled LDS image)
    int j0 = wid*2, j1 = j0 + 1;
    int r0 = j0*16 + (lane >> 2), r1 = j1*16 + (lane >> 2);
    int c8 = (lane & 3) * 8;
    const unsigned short* gA0 = Zcat + (size_t)(mt*128 + r0)*256 + c8;
    const unsigned short* gA1 = Zcat + (size_t)(mt*128 + r1)*256 + c8;
    const unsigned short* gB0 = Ecat + (size_t)(nt*128 + r0)*256 + c8;
    const unsigned short* gB1 = Ecat + (size_t)(nt*128 + r1)*256 + c8;
    unsigned short* lA0s0 = As0 + j0*512;  unsigned short* lA1s0 = As0 + j1*512;
    unsigned short* lA0s1 = As1 + j0*512;  unsigned short* lA1s1 = As1 + j1*512;
    unsigned short* lB0s0 = Bs0 + j0*512;  unsigned short* lB1s0 = Bs0 + j1*512;
    unsigned short* lB0s1 = Bs1 + j0*512;  unsigned short* lB1s1 = Bs1 + j1*512;

    f32x4 acc[4][4];
    #pragma unroll
    for (int i = 0; i < 4; ++i)
        #pragma unroll
        for (int j = 0; j < 4; ++j) acc[i][j] = (f32x4){0.f,0.f,0.f,0.f};

    // fragment read: row = frow(+16i), quarter q=lane>>4 -> LDS quarter q^s(frow)
    int frow = lane & 15, q = lane >> 4;
    int sw = (frow >> 1) & 3;
    const unsigned short* a0Base = As0 + (wm + frow)*32 + ((q ^ sw) * 8);
    const unsigned short* a1Base = As1 + (wm + frow)*32 + ((q ^ sw) * 8);
    const unsigned short* b0Base = Bs0 + (wn + frow)*32 + ((q ^ sw) * 8);
    const unsigned short* b1Base = Bs1 + (wn + frow)*32 + ((q ^ sw) * 8);

    // prologue: stage chunk 0 into ping
    gload_lds16(gA0, lA0s0);
    gload_lds16(gA1, lA1s0);
    gload_lds16(gB0, lB0s0);
    gload_lds16(gB1, lB1s0);
    __syncthreads();

    #pragma unroll 1
    for (int c = 0; c < 8; ++c) {
        int nxt = c + 1;
        if (nxt < 8) {                 // stage next chunk into the other buffer
            int aOff = nxt * 32;
            if (nxt & 1) {
                gload_lds16(gA0 + aOff, lA0s1);
                gload_lds16(gA1 + aOff, lA1s1);
                gload_lds16(gB0 + aOff, lB0s1);
                gload_lds16(gB1 + aOff, lB1s1);
            } else {
                gload_lds16(gA0 + aOff, lA0s0);
                gload_lds16(gA1 + aOff, lA1s0);
                gload_lds16(gB0 + aOff, lB0s0);
                gload_lds16(gB1 + aOff, lB1s0);
            }
        }
        const unsigned short* aB = (c & 1) ? a1Base : a0Base;
        const unsigned short* bB = (c & 1) ? b1Base : b0Base;
        f16x8 af[4], bfr[4];
        #pragma unroll
        for (int i = 0; i < 4; ++i) bfr[i] = *(const f16x8*)(bB + i*16*32);
        #pragma unroll
        for (int i = 0; i < 4; ++i) af[i] = *(const f16x8*)(aB + i*16*32);
        #pragma unroll
        for (int i = 0; i < 4; ++i)
            #pragma unroll
            for (int j = 0; j < 4; ++j)
                acc[i][j] = __builtin_amdgcn_mfma_f32_16x16x32_f16(af[i], bfr[j], acc[i][j], 0, 0, 0);
        __syncthreads();   // drains this phase's loads AFTER the MFMA cluster
    }

    // ---- epilogue: D layout n = lane&15 (frow), m = q*4 + reg (+16i) ----
    // Two passes (i in {0,1} then {2,3}); reduce buffer aliases staging LDS.
    float ensr[4]; int nn[4];
    #pragma unroll
    for (int j = 0; j < 4; ++j) {
        int nl = wn + j*16 + frow;
        nn[j] = nt*128 + nl;
        ensr[j] = ens[nl];
    }
    uint4* P = (uint4*)UB;                 // [16][129] uint4
    int gbase = wng*64 + wmg*32 + q*4;     // + i2*16 + r per store

    #pragma unroll
    for (int ih = 0; ih < 2; ++ih) {
        // phase 1: local top-2 over j columns, scatter (v1,i1,v2) to P[frow][g]
        #pragma unroll
        for (int i2 = 0; i2 < 2; ++i2) {
            int i = ih*2 + i2;
            #pragma unroll
            for (int r = 0; r < 4; ++r) {
                float s0 = fmaf(-0.0078125f, acc[i][0][r], ensr[0]);  // 2/256 e-unscale
                float s1 = fmaf(-0.0078125f, acc[i][1][r], ensr[1]);
                float s2 = fmaf(-0.0078125f, acc[i][2][r], ensr[2]);
                float s3 = fmaf(-0.0078125f, acc[i][3][r], ensr[3]);
                float v1 = s0; int i1 = nn[0];
                float v2 = fmaxf(v1, s1);
                if (s1 < v1) i1 = nn[1];
                v1 = fminf(v1, s1);
                v2 = fminf(v2, fmaxf(v1, s2));
                if (s2 < v1) i1 = nn[2];
                v1 = fminf(v1, s2);
                v2 = fminf(v2, fmaxf(v1, s3));
                if (s3 < v1) i1 = nn[3];
                v1 = fminf(v1, s3);
                P[frow*129 + gbase + i2*16 + r] =
                    make_uint4(__float_as_uint(v1), (uint32)i1, __float_as_uint(v2), 0u);
            }
        }
        __syncthreads();
        // phase 2: 128 threads, one (col-half, row) each: merge 16 frow partials
        if (t < 128) {
            const uint4* base = P + t;
            uint4 e0 = base[0];
            float v1 = __uint_as_float(e0.x); int i1 = (int)e0.y;
            float v2 = __uint_as_float(e0.z);
            #pragma unroll
            for (int f = 1; f < 16; ++f) {
                uint4 e = base[f*129];
                float ov1 = __uint_as_float(e.x), ov2 = __uint_as_float(e.z);
                v2 = fminf(fminf(v2, ov2), fmaxf(v1, ov1));
                if (ov1 < v1) i1 = (int)e.y;
                v1 = fminf(v1, ov1);
            }
            fv1[t] = v1; fi1[t] = i1; fv2[t] = v2;
        }
        __syncthreads();
        // final: merge the two col-halves, write partials
        if (t < 64) {
            float v1 = fv1[t], v2 = fv2[t]; int i1 = fi1[t];
            float ov1 = fv1[64+t], ov2 = fv2[64+t];
            v2 = fminf(fminf(v2, ov2), fmaxf(v1, ov1));
            if (ov1 < v1) i1 = fi1[64+t];
            v1 = fminf(v1, ov1);
            size_t o = (size_t)nt * N_ROWS + mt*128 + (t>>5)*64 + ih*32 + (t&31);
            pv[o] = v1; pi[o] = i1; pv2[o] = v2;
        }
        // ih=1 phase-1 P-writes are safe: all P-reads completed before the
        // post-phase-2 barrier; fv*-reads above touch disjoint memory.
    }
}

// merge 64 n-tile partials per row; flag rows with gap < DELTA for np-exact rescan
__global__ void k_merge(const float* __restrict__ pv, const int* __restrict__ pi,
                        const float* __restrict__ pv2,
                        float* __restrict__ out_idx_f, int* __restrict__ idxint,
                        int* __restrict__ flagcnt, int* __restrict__ flagged) {
    int g = blockIdx.x * 256 + threadIdx.x;
    float B1 = FLT_MAX, B2 = FLT_MAX; int I1 = 0;
    #pragma unroll 1
    for (int p = 0; p < NTILES; ++p) {   // ascending p == ascending k
        size_t o = (size_t)p * N_ROWS + g;
        float v1 = pv[o], v2 = pv2[o]; int i1 = pi[o];
        if (v1 < B1) { B2 = fminf(B1, v2); B1 = v1; I1 = i1; }
        else B2 = fminf(B2, v1);
    }
    out_idx_f[g] = (float)I1;
    idxint[g] = I1;
    if (B2 - B1 < DELTA) {
        int slot = atomicAdd(flagcnt, 1);
        flagged[slot] = g;
    }
}

// Phase B: np-exact fp32 rescan (validated round-3 semantics). Task =
// (k-slice of 1024, group of RB flagged rows); zn computed in-kernel (np order);
// result via atomicMin on order-packed (score,idx).
__global__ void k_phaseB(const float* __restrict__ Z, const float* __restrict__ ET,
                         const float* __restrict__ enorm,
                         const int* __restrict__ flagcnt, const int* __restrict__ flagged,
                         uint64* __restrict__ packed) {
    __shared__ float zl[RB][256];
    __shared__ float znl[RB];
    __shared__ int rows[RB];
    __shared__ float sv[256]; __shared__ int si[256];
    int t = threadIdx.x;
    int cnt = *flagcnt; if (cnt > N_ROWS) cnt = N_ROWS;
    int ngrp = (cnt + RB - 1) / RB;
    int ntask = ngrp * 8;
    #pragma unroll 1
    for (int task = blockIdx.x; task < ntask; task += gridDim.x) {
        int slice = task & 7;
        int g0 = (task >> 3) * RB;
        __syncthreads();
        if (t < RB) {
            int f = g0 + t;
            rows[t] = flagged[f < cnt ? f : g0];   // clamp dup: recompute harmless
        }
        __syncthreads();
        #pragma unroll
        for (int rr = 0; rr < RB; ++rr) zl[rr][t] = Z[(size_t)rows[rr]*EDIM + t];
        __syncthreads();
        if (t < RB) znl[t] = np_pairwise_sumsq(&zl[t][0]);
        __syncthreads();

        float acc[RB][4];
        #pragma unroll
        for (int rr = 0; rr < RB; ++rr)
            #pragma unroll
            for (int c = 0; c < 4; ++c) acc[rr][c] = 0.f;
        const float* eb = ET + slice*1024 + t;
        #pragma unroll 1
        for (int d = 0; d < 256; ++d) {           // sequential ascending d (np order)
            const float* ep = eb + (size_t)d * NE;
            float v0 = ep[0], v1 = ep[256], v2 = ep[512], v3 = ep[768];
            #pragma unroll
            for (int rr = 0; rr < RB; ++rr) {
                float zd = zl[rr][d];
                acc[rr][0] = fmaf(zd, v0, acc[rr][0]);
                acc[rr][1] = fmaf(zd, v1, acc[rr][1]);
                acc[rr][2] = fmaf(zd, v2, acc[rr][2]);
                acc[rr][3] = fmaf(zd, v3, acc[rr][3]);
            }
        }
        #pragma unroll 1
        for (int rr = 0; rr < RB; ++rr) {
            int row = rows[rr];
            float zn = znl[rr];
            float bv = FLT_MAX; int bi = 0x7fffffff;
            {
#pragma clang fp contract(off)
                #pragma unroll
                for (int c = 0; c < 4; ++c) {
                    int k = slice*1024 + c*256 + t;
                    float S  = zn + enorm[k];
                    float tw = 2.0f * acc[rr][c];
                    float sc = S - tw;
                    if (sc < bv || (sc == bv && k < bi)) { bv = sc; bi = k; }
                }
            }
            sv[t] = bv; si[t] = bi;
            __syncthreads();
            for (int st = 128; st > 0; st >>= 1) {
                if (t < st) {
                    float ov = sv[t+st]; int oi = si[t+st];
                    if (ov < sv[t] || (ov == sv[t] && oi < si[t])) { sv[t] = ov; si[t] = oi; }
                }
                __syncthreads();
            }
            if (t == 0) {
                uint64 pk = ((uint64)float_key(sv[0]) << 32) | (uint32)si[0];
                atomicMin(packed + row, pk);
            }
            __syncthreads();
        }
    }
}

// tail A: apply phase-B idx fix, write z_q_st + loss partial, histogram idx.
__global__ void k_taila(const float* __restrict__ Z, const float* __restrict__ E,
                        int* __restrict__ idxint, const uint64* __restrict__ packed,
                        float* __restrict__ out0, float* __restrict__ out_idx_f,
                        int* __restrict__ hist, float* __restrict__ lossp) {
    __shared__ float wsum[4];
    int t = threadIdx.x;
    int w = t >> 6, lane = t & 63;
    int row = blockIdx.x * 4 + w;
    int idx = idxint[row];
    uint64 pk = packed[row];
    if (pk != 0xFFFFFFFFFFFFFFFFull) {          // flagged: exact rescan result
        idx = (int)(uint32)(pk & 0xffffffffu);
        if (lane == 0) { out_idx_f[row] = (float)idx; idxint[row] = idx; }
    }
    float4 z4 = ((const float4*)Z)[(size_t)row * 64 + lane];
    float4 e4 = ((const float4*)E)[(size_t)idx * 64 + lane];
    float4 d4; d4.x = e4.x - z4.x; d4.y = e4.y - z4.y; d4.z = e4.z - z4.z; d4.w = e4.w - z4.w;
    float4 o;  o.x = z4.x + d4.x;  o.y = z4.y + d4.y;  o.z = z4.z + d4.z;  o.w = z4.w + d4.w;
    ((float4*)out0)[(size_t)row * 64 + lane] = o;
    float q2 = d4.x*d4.x + d4.y*d4.y + d4.z*d4.z + d4.w*d4.w;
    #pragma unroll
    for (int off = 32; off > 0; off >>= 1) q2 += __shfl_down(q2, off, 64);
    if (lane == 0) { wsum[w] = q2; atomicAdd(&hist[idx], 1); }
    __syncthreads();
    if (t == 0) lossp[blockIdx.x] = wsum[0] + wsum[1] + wsum[2] + wsum[3];
}

// exclusive prefix-scan of hist[8192] -> offs and cursor (one block)
__global__ void k_scan(const int* __restrict__ hist,
                       int* __restrict__ cursor, int* __restrict__ offs) {
    __shared__ int part[256];
    int t = threadIdx.x;
    int loc[32];
    int s = 0;
    #pragma unroll
    for (int j = 0; j < 32; ++j) { loc[j] = s; s += hist[t*32 + j]; }
    part[t] = s;
    __syncthreads();
    // Hillis-Steele inclusive scan over 256 partials
    #pragma unroll
    for (int off = 1; off < 256; off <<= 1) {
        int u = (t >= off) ? part[t - off] : 0;
        __syncthreads();
        part[t] += u;
        __syncthreads();
    }
    int base = part[t] - s;   // exclusive base for this thread's 32 codes
    #pragma unroll
    for (int j = 0; j < 32; ++j) {
        int o = base + loc[j];
        offs[t*32 + j] = o;
        cursor[t*32 + j] = o;
    }
}

// tail B: scatter row ids into per-code segments
__global__ void k_tailb(const int* __restrict__ idxint,
                        int* __restrict__ cursor, int* __restrict__ rowlist) {
    int g = blockIdx.x * 256 + threadIdx.x;
    int idx = idxint[g];
    int pos = atomicAdd(&cursor[idx], 1);
    rowlist[pos] = g;
}

// dw gather-sum per code + cl divide + loss reduce (block 0)
__global__ void k_dw(const float* __restrict__ Z, const int* __restrict__ hist,
                     const int* __restrict__ offs, const int* __restrict__ rowlist,
                     const float* __restrict__ lossp,
                     float* __restrict__ out3, float* __restrict__ out2) {
    __shared__ double red[256];
    int k = blockIdx.x;
    int t = threadIdx.x;
    int cnt = hist[k];
    int start = offs[k];
    float s0 = 0.f, s1 = 0.f;
    int j = 0;
    #pragma unroll 1
    for (; j + 1 < cnt; j += 2) {
        int ra = rowlist[start + j];
        int rb = rowlist[start + j + 1];
        s0 += Z[(size_t)ra * EDIM + t];
        s1 += Z[(size_t)rb * EDIM + t];
    }
    if (j < cnt) s0 += Z[(size_t)rowlist[start + j] * EDIM + t];
    float sum = s0 + s1;
    float cl = ((float)cnt + 1e-5f) / (32768.0f + 8192.0f * 1e-5f) * 32768.0f;
    out3[(size_t)k * EDIM + t] = sum / cl;
    if (k == 0) {
        double s = 0.0;
        #pragma unroll 1
        for (int p = t; p < 8192; p += 256) s += (double)lossp[p];
        red[t] = s;
        __syncthreads();
        #pragma unroll
        for (int st = 128; st > 0; st >>= 1) {
            if (t < st) red[t] += red[t + st];
            __syncthreads();
        }
        if (t == 0) out2[0] = 0.25f * (float)(red[0] / 8388608.0);
    }
}

extern "C" void kernel_launch(void* const* d_in, const int* in_sizes, int n_in,
                              void* d_out, int out_size, void* d_ws, size_t ws_size,
                              hipStream_t stream) {
    const float* Z = (const float*)d_in[0];   // [32768, 256]
    const float* E = (const float*)d_in[1];   // [8192, 256]
    float* out  = (float*)d_out;
    float* out0 = out;                         // z_q_st  (8388608)
    float* out1 = out + 8388608;               // idx as float (32768)
    float* out2 = out1 + 32768;                // loss (1)
    float* out3 = out2 + 1;                    // new_embeddings (2097152)

    char* ws = (char*)d_ws;
    unsigned short* Zcat = (unsigned short*)(ws + OFF_ZCAT);
    unsigned short* Ecat = (unsigned short*)(ws + OFF_ECAT);
    float*  ET      = (float*)(ws + OFF_ET);
    float*  enorm   = (float*)(ws + OFF_EN);
    float*  pv      = (float*)(ws + OFF_PV);
    int*    pi      = (int*)  (ws + OFF_PI);
    float*  pv2     = (float*)(ws + OFF_PV2);
    int*    idxint  = (int*)  (ws + OFF_IDX);
    int*    hist    = (int*)  (ws + OFF_BINS);
    uint64* packed  = (uint64*)(ws + OFF_PACKED);
    int*    flagcnt = (int*)  (ws + OFF_FLAGCNT);
    int*    flagged = (int*)  (ws + OFF_FLAGGED);
    float*  lossp   = (float*)(ws + OFF_PV);                 // after merge
    int*    rowlist = (int*)  (ws + OFF_PV + 32768);         // after merge
    int*    cursor  = (int*)  (ws + OFF_PV2);                // after merge
    int*    offs    = (int*)  (ws + OFF_PV2 + 32768);        // after merge

    k_prep   <<<5184,         256, 0, stream>>>(Z, E, Zcat, Ecat, ET, enorm,
                                                packed, hist, flagcnt);
    k_gemm   <<<256 * NTILES, 256, 0, stream>>>(Zcat, Ecat, enorm, pv, pi, pv2);
    k_merge  <<<N_ROWS / 256, 256, 0, stream>>>(pv, pi, pv2, out1, idxint, flagcnt, flagged);
    k_phaseB <<<2048,         256, 0, stream>>>(Z, ET, enorm, flagcnt, flagged, packed);
    k_taila  <<<N_ROWS / 4,   256, 0, stream>>>(Z, E, idxint, packed, out0, out1, hist, lossp);
    k_scan   <<<1,            256, 0, stream>>>(hist, cursor, offs);
    k_tailb  <<<N_ROWS / 256, 256, 0, stream>>>(idxint, cursor, rowlist);
    k_dw     <<<NE,           256, 0, stream>>>(Z, hist, offs, rowlist, lossp, out3, out2);
}

// Round 12
// 417.184 us; speedup vs baseline: 1.1370x; 1.0302x over previous
//
#include <hip/hip_runtime.h>
#include <math.h>
#include <float.h>

#define N_ROWS 32768
#define EDIM 256
#define NE 8192
#define NTILES 64            // 8192 / 128 n-tiles -> partials per row
#define DELTA 1.6e-3f        // rescue margin: ~5.7 sigma of f16 gap error
#define RB 8                 // rows per phase-B group (16 regressed: phaseB is parallelism-bound, round 10)

typedef unsigned int uint32;
typedef unsigned long long uint64;
typedef __attribute__((ext_vector_type(8))) _Float16 f16x8;  // 8 f16 = 4 VGPRs
typedef __attribute__((ext_vector_type(4))) float f32x4;

// ---- workspace layout (bytes) ----
#define OFF_ZCAT    ((size_t)0)           // 32768 x 256 f16, quarter-swizzled = 16777216
#define OFF_ECAT    ((size_t)33554432)    //  8192 x 256 f16 (256*E), quarter-swizzled = 4194304
#define OFF_ET      ((size_t)37748736)    //  256 x 8192 f32 (E^T) = 8388608
#define OFF_EN      ((size_t)46268416)    //  8192 f
#define OFF_PV      ((size_t)46301184)    // 64 x 32768 f  (after merge: lossp @+0, rowlist @+32768)
#define OFF_PI      ((size_t)54689792)    // 64 x 32768 i
#define OFF_PV2     ((size_t)63078400)    // 64 x 32768 f  (after merge: cursor @+0, offs @+32768)
#define OFF_IDX     ((size_t)71467008)    // 32768 i
#define OFF_BINS    ((size_t)71598080)    //  8192 i (hist)
#define OFF_PACKED  ((size_t)71630848)    // 32768 u64 = 262144
#define OFF_FLAGCNT ((size_t)71892992)    // int (padded)
#define OFF_FLAGGED ((size_t)71893504)    // 32768 i

__device__ __forceinline__ uint32 pack2_f16(float a, float b) {
    _Float16 ha = (_Float16)a;   // v_cvt_f16_f32, RNE
    _Float16 hb = (_Float16)b;
    unsigned short ua = __builtin_bit_cast(unsigned short, ha);
    unsigned short ub = __builtin_bit_cast(unsigned short, hb);
    return (uint32)ua | ((uint32)ub << 16);
}

__device__ __forceinline__ void gload_lds16(const void* g, void* l) {
    __builtin_amdgcn_global_load_lds(
        (const __attribute__((address_space(1))) uint32*)g,
        (__attribute__((address_space(3))) uint32*)l, 16, 0, 0);
}

// numpy pairwise-sum emulation of sum(a*a) for n=256 (validated round 3)
__device__ __forceinline__ float np_pairwise_sumsq(const float* a) {
#pragma clang fp contract(off)
    float h0, h1;
    #pragma unroll 1
    for (int hb = 0; hb < 2; ++hb) {
        const float* p = a + hb * 128;
        float r0=p[0]*p[0], r1=p[1]*p[1], r2=p[2]*p[2], r3=p[3]*p[3],
              r4=p[4]*p[4], r5=p[5]*p[5], r6=p[6]*p[6], r7=p[7]*p[7];
        #pragma unroll 1
        for (int i = 8; i < 128; i += 8) {
            r0 += p[i+0]*p[i+0]; r1 += p[i+1]*p[i+1];
            r2 += p[i+2]*p[i+2]; r3 += p[i+3]*p[i+3];
            r4 += p[i+4]*p[i+4]; r5 += p[i+5]*p[i+5];
            r6 += p[i+6]*p[i+6]; r7 += p[i+7]*p[i+7];
        }
        float s = ((r0+r1)+(r2+r3))+((r4+r5)+(r6+r7));
        if (hb == 0) h0 = s; else h1 = s;
    }
    return h0 + h1;
}

// Fused prep + init: [0,4096) convert Z; [4096,5120) convert E (+ET via LDS
// transpose + enorm from the same LDS tile); [5120,5152) packed=~0;
// [5152,5184) hist=0 (+flagcnt).
__global__ void k_prep(const float* __restrict__ Z, const float* __restrict__ E,
                       unsigned short* __restrict__ Zcat, unsigned short* __restrict__ Ecat,
                       float* __restrict__ ET, float* __restrict__ en,
                       uint64* __restrict__ packed, int* __restrict__ hist,
                       int* __restrict__ flagcnt) {
    __shared__ float tile[8][264];   // [r8][k], padded row
    int b = blockIdx.x;
    int t = threadIdx.x;
    if (b < 4096) {
        // Zcat: per row 8 chunks of 32 k, each chunk 4 quarters of 8 f16.
        // Global slot (r,c,q) holds logical quarter q ^ s(r), s(r)=(r>>1)&3.
        int r = b * 8 + (t >> 5);
        int u = t & 31;
        int c = u >> 2, q = u & 3;
        int lq = q ^ ((r >> 1) & 3);
        int k0 = c * 32 + lq * 8;
        const float4* zp = (const float4*)(Z + (size_t)r * EDIM + k0);
        float4 a = zp[0], bb = zp[1];
        float f[8] = {a.x,a.y,a.z,a.w,bb.x,bb.y,bb.z,bb.w};
        uint32 o[4];
        #pragma unroll
        for (int j = 0; j < 4; ++j) o[j] = pack2_f16(f[2*j], f[2*j+1]);
        *(uint4*)(Zcat + (size_t)r * 256 + c * 32 + q * 8) = make_uint4(o[0],o[1],o[2],o[3]);
    } else if (b < 5120) {
        // Ecat: f16 of 256*E (scale dodges f16 denormals); same swizzle.
        // ET (f32, unscaled, exact) via LDS transpose; enorm (np-exact) from
        // the same tile (rows are in natural k order).
        int eb = b - 4096;
        int r8 = t >> 5;
        int r = eb * 8 + r8;
        int u = t & 31;
        int c = u >> 2, q = u & 3;
        int lq = q ^ ((r >> 1) & 3);
        int k0 = c * 32 + lq * 8;
        const float4* ep = (const float4*)(E + (size_t)r * EDIM + k0);
        float4 a = ep[0], bb = ep[1];
        float f[8] = {a.x,a.y,a.z,a.w,bb.x,bb.y,bb.z,bb.w};
        uint32 o[4];
        #pragma unroll
        for (int j = 0; j < 4; ++j) o[j] = pack2_f16(256.0f*f[2*j], 256.0f*f[2*j+1]);
        *(uint4*)(Ecat + (size_t)r * 256 + c * 32 + q * 8) = make_uint4(o[0],o[1],o[2],o[3]);
        *(float4*)&tile[r8][k0]     = make_float4(f[0], f[1], f[2], f[3]);
        *(float4*)&tile[r8][k0 + 4] = make_float4(f[4], f[5], f[6], f[7]);
        __syncthreads();
        float4 lo, hi;
        lo.x = tile[0][t]; lo.y = tile[1][t]; lo.z = tile[2][t]; lo.w = tile[3][t];
        hi.x = tile[4][t]; hi.y = tile[5][t]; hi.z = tile[6][t]; hi.w = tile[7][t];
        float* dst = ET + (size_t)t * NE + eb * 8;
        *(float4*)dst = lo;
        *(float4*)(dst + 4) = hi;
        if (t < 8) en[eb * 8 + t] = np_pairwise_sumsq(&tile[t][0]);
    } else if (b < 5152) {
        int i = (b - 5120) * 256 + t;
        #pragma unroll
        for (int j = 0; j < 4; ++j) packed[i + j*8192] = 0xFFFFFFFFFFFFFFFFull;
    } else {
        hist[(b - 5152) * 256 + t] = 0;
        if (b == 5152 && t == 0) *flagcnt = 0;
    }
}

__device__ __forceinline__ uint32 float_key(float v) {
    uint32 b = __float_as_uint(v);
    return (b & 0x80000000u) ? ~b : (b | 0x80000000u);   // monotone total order
}

// Phase A: f16 z . f16 (256 e) MFMA GEMM, K=256. Round-7 ping-pong structure
// (best measured: ~187us, 0 conflicts; depth-2 counted-vmcnt regressed via
// occupancy loss (r9); epilogue tree regressed via LDS conflicts (r10)).
// Score = en - (2/256)*dot. Epilogue: float-domain top-2, serial chains;
// phase-2 fused with final merge (64 threads merge both wng chains, write
// partials directly -- one fewer barrier+LDS round-trip per ih pass; exact
// same multiset mins; tie-index diffs are gap-0 -> DELTA-flagged -> phaseB).
// Reduce buffer [frow][group] stride-129 uint4: zero bank conflicts (r4).
__global__ __launch_bounds__(256, 4) void k_gemm(
    const unsigned short* __restrict__ Zcat, const unsigned short* __restrict__ Ecat,
    const float* __restrict__ enorm,
    float* __restrict__ pv, int* __restrict__ pi, float* __restrict__ pv2)
{
    __shared__ __align__(16) char UB[33024];   // staging (32KB) / reduce 16*129*16B
    __shared__ float ens[128];

    unsigned short* As0 = (unsigned short*)(UB);
    unsigned short* As1 = (unsigned short*)(UB + 8192);
    unsigned short* Bs0 = (unsigned short*)(UB + 16384);
    unsigned short* Bs1 = (unsigned short*)(UB + 24576);

    int t = threadIdx.x;
    int nt = blockIdx.x & 63, mt = blockIdx.x >> 6;   // n fastest: A-band L2 reuse
    int wid = t >> 6, lane = t & 63;
    int wmg = wid >> 1, wng = wid & 1;
    int wm = wmg * 64, wn = wng * 64;

    if (t < 128) ens[t] = enorm[nt*128 + t];

    // staging: wave wid fills LDS j-blocks {2w,2w+1}; lane -> row j*16+(lane>>2),
    // quarter lane&3 (matches global slot layout -> swizzled LDS image)
    int j0 = wid*2, j1 = j0 + 1;
    int r0 = j0*16 + (lane >> 2), r1 = j1*16 + (lane >> 2);
    int c8 = (lane & 3) * 8;
    const unsigned short* gA0 = Zcat + (size_t)(mt*128 + r0)*256 + c8;
    const unsigned short* gA1 = Zcat + (size_t)(mt*128 + r1)*256 + c8;
    const unsigned short* gB0 = Ecat + (size_t)(nt*128 + r0)*256 + c8;
    const unsigned short* gB1 = Ecat + (size_t)(nt*128 + r1)*256 + c8;
    unsigned short* lA0s0 = As0 + j0*512;  unsigned short* lA1s0 = As0 + j1*512;
    unsigned short* lA0s1 = As1 + j0*512;  unsigned short* lA1s1 = As1 + j1*512;
    unsigned short* lB0s0 = Bs0 + j0*512;  unsigned short* lB1s0 = Bs0 + j1*512;
    unsigned short* lB0s1 = Bs1 + j0*512;  unsigned short* lB1s1 = Bs1 + j1*512;

    f32x4 acc[4][4];
    #pragma unroll
    for (int i = 0; i < 4; ++i)
        #pragma unroll
        for (int j = 0; j < 4; ++j) acc[i][j] = (f32x4){0.f,0.f,0.f,0.f};

    // fragment read: row = frow(+16i), quarter q=lane>>4 -> LDS quarter q^s(frow)
    int frow = lane & 15, q = lane >> 4;
    int sw = (frow >> 1) & 3;
    const unsigned short* a0Base = As0 + (wm + frow)*32 + ((q ^ sw) * 8);
    const unsigned short* a1Base = As1 + (wm + frow)*32 + ((q ^ sw) * 8);
    const unsigned short* b0Base = Bs0 + (wn + frow)*32 + ((q ^ sw) * 8);
    const unsigned short* b1Base = Bs1 + (wn + frow)*32 + ((q ^ sw) * 8);

    // prologue: stage chunk 0 into ping
    gload_lds16(gA0, lA0s0);
    gload_lds16(gA1, lA1s0);
    gload_lds16(gB0, lB0s0);
    gload_lds16(gB1, lB1s0);
    __syncthreads();

    #pragma unroll 1
    for (int c = 0; c < 8; ++c) {
        int nxt = c + 1;
        if (nxt < 8) {                 // stage next chunk into the other buffer
            int aOff = nxt * 32;
            if (nxt & 1) {
                gload_lds16(gA0 + aOff, lA0s1);
                gload_lds16(gA1 + aOff, lA1s1);
                gload_lds16(gB0 + aOff, lB0s1);
                gload_lds16(gB1 + aOff, lB1s1);
            } else {
                gload_lds16(gA0 + aOff, lA0s0);
                gload_lds16(gA1 + aOff, lA1s0);
                gload_lds16(gB0 + aOff, lB0s0);
                gload_lds16(gB1 + aOff, lB1s0);
            }
        }
        const unsigned short* aB = (c & 1) ? a1Base : a0Base;
        const unsigned short* bB = (c & 1) ? b1Base : b0Base;
        f16x8 af[4], bfr[4];
        #pragma unroll
        for (int i = 0; i < 4; ++i) bfr[i] = *(const f16x8*)(bB + i*16*32);
        #pragma unroll
        for (int i = 0; i < 4; ++i) af[i] = *(const f16x8*)(aB + i*16*32);
        #pragma unroll
        for (int i = 0; i < 4; ++i)
            #pragma unroll
            for (int j = 0; j < 4; ++j)
                acc[i][j] = __builtin_amdgcn_mfma_f32_16x16x32_f16(af[i], bfr[j], acc[i][j], 0, 0, 0);
        __syncthreads();   // drains this phase's loads AFTER the MFMA cluster
    }

    // ---- epilogue: D layout n = lane&15 (frow), m = q*4 + reg (+16i) ----
    // Two passes (i in {0,1} then {2,3}); reduce buffer aliases staging LDS.
    float ensr[4]; int nn[4];
    #pragma unroll
    for (int j = 0; j < 4; ++j) {
        int nl = wn + j*16 + frow;
        nn[j] = nt*128 + nl;
        ensr[j] = ens[nl];
    }
    uint4* P = (uint4*)UB;                 // [16][129] uint4
    int gbase = wng*64 + wmg*32 + q*4;     // + i2*16 + r per store

    #pragma unroll
    for (int ih = 0; ih < 2; ++ih) {
        // phase 1: local top-2 over j columns, scatter (v1,i1,v2) to P[frow][g]
        #pragma unroll
        for (int i2 = 0; i2 < 2; ++i2) {
            int i = ih*2 + i2;
            #pragma unroll
            for (int r = 0; r < 4; ++r) {
                float s0 = fmaf(-0.0078125f, acc[i][0][r], ensr[0]);  // 2/256 e-unscale
                float s1 = fmaf(-0.0078125f, acc[i][1][r], ensr[1]);
                float s2 = fmaf(-0.0078125f, acc[i][2][r], ensr[2]);
                float s3 = fmaf(-0.0078125f, acc[i][3][r], ensr[3]);
                float v1 = s0; int i1 = nn[0];
                float v2 = fmaxf(v1, s1);
                if (s1 < v1) i1 = nn[1];
                v1 = fminf(v1, s1);
                v2 = fminf(v2, fmaxf(v1, s2));
                if (s2 < v1) i1 = nn[2];
                v1 = fminf(v1, s2);
                v2 = fminf(v2, fmaxf(v1, s3));
                if (s3 < v1) i1 = nn[3];
                v1 = fminf(v1, s3);
                P[frow*129 + gbase + i2*16 + r] =
                    make_uint4(__float_as_uint(v1), (uint32)i1, __float_as_uint(v2), 0u);
            }
        }
        __syncthreads();
        // phase 2 (fused final): 64 threads, one output row each; merge both
        // wng chains (g=t and g=t+64 across 16 frows), write partials directly
        if (t < 64) {
            const uint4* b0 = P + t;
            uint4 e0 = b0[0];
            float v1 = __uint_as_float(e0.x); int i1 = (int)e0.y;
            float v2 = __uint_as_float(e0.z);
            #pragma unroll
            for (int f = 1; f < 16; ++f) {
                uint4 e = b0[f*129];
                float ov1 = __uint_as_float(e.x), ov2 = __uint_as_float(e.z);
                v2 = fminf(fminf(v2, ov2), fmaxf(v1, ov1));
                if (ov1 < v1) i1 = (int)e.y;
                v1 = fminf(v1, ov1);
            }
            const uint4* b1 = P + 64 + t;
            #pragma unroll
            for (int f = 0; f < 16; ++f) {
                uint4 e = b1[f*129];
                float ov1 = __uint_as_float(e.x), ov2 = __uint_as_float(e.z);
                v2 = fminf(fminf(v2, ov2), fmaxf(v1, ov1));
                if (ov1 < v1) i1 = (int)e.y;
                v1 = fminf(v1, ov1);
            }
            size_t o = (size_t)nt * N_ROWS + mt*128 + (t>>5)*64 + ih*32 + (t&31);
            pv[o] = v1; pi[o] = i1; pv2[o] = v2;
        }
        __syncthreads();
        // barrier protects ih=1 phase-1 P-writes from ih=0 phase-2 reads.
    }
}

// merge 64 n-tile partials per row, 4 threads/row (16 serial each + shfl
// tree) -- 8 waves/CU vs 2 for the 1-thread/row version; exact top-2 merge.
// Flag rows with gap < DELTA for np-exact rescan.
__global__ void k_merge(const float* __restrict__ pv, const int* __restrict__ pi,
                        const float* __restrict__ pv2,
                        float* __restrict__ out_idx_f, int* __restrict__ idxint,
                        int* __restrict__ flagcnt, int* __restrict__ flagged) {
    int t = threadIdx.x;
    int sub = t & 3;
    int g = blockIdx.x * 64 + (t >> 2);
    float B1 = FLT_MAX, B2 = FLT_MAX; int I1 = 0;
    #pragma unroll 1
    for (int p = sub*16; p < sub*16 + 16; ++p) {   // ascending within sub
        size_t o = (size_t)p * N_ROWS + g;
        float v1 = pv[o], v2 = pv2[o]; int i1 = pi[o];
        if (v1 < B1) { B2 = fminf(B1, v2); B1 = v1; I1 = i1; }
        else B2 = fminf(B2, v1);
    }
    // exact top-2 merge across the 4 sub-lanes (adjacent lanes)
    #pragma unroll
    for (int off = 1; off < 4; off <<= 1) {
        float ov1 = __shfl_xor(B1, off, 64);
        int   oi1 = __shfl_xor(I1, off, 64);
        float ov2 = __shfl_xor(B2, off, 64);
        B2 = fminf(fminf(B2, ov2), fmaxf(B1, ov1));
        if (ov1 < B1) I1 = oi1;
        B1 = fminf(B1, ov1);
    }
    if (sub == 0) {
        out_idx_f[g] = (float)I1;
        idxint[g] = I1;
        if (B2 - B1 < DELTA) {
            int slot = atomicAdd(flagcnt, 1);
            flagged[slot] = g;
        }
    }
}

// Phase B: np-exact fp32 rescan (validated round-3 semantics). Task =
// (k-slice of 1024, group of RB flagged rows); zn computed in-kernel (np order);
// result via atomicMin on order-packed (score,idx).
__global__ void k_phaseB(const float* __restrict__ Z, const float* __restrict__ ET,
                         const float* __restrict__ enorm,
                         const int* __restrict__ flagcnt, const int* __restrict__ flagged,
                         uint64* __restrict__ packed) {
    __shared__ float zl[RB][256];
    __shared__ float znl[RB];
    __shared__ int rows[RB];
    __shared__ float sv[256]; __shared__ int si[256];
    int t = threadIdx.x;
    int cnt = *flagcnt; if (cnt > N_ROWS) cnt = N_ROWS;
    int ngrp = (cnt + RB - 1) / RB;
    int ntask = ngrp * 8;
    #pragma unroll 1
    for (int task = blockIdx.x; task < ntask; task += gridDim.x) {
        int slice = task & 7;
        int g0 = (task >> 3) * RB;
        __syncthreads();
        if (t < RB) {
            int f = g0 + t;
            rows[t] = flagged[f < cnt ? f : g0];   // clamp dup: recompute harmless
        }
        __syncthreads();
        #pragma unroll
        for (int rr = 0; rr < RB; ++rr) zl[rr][t] = Z[(size_t)rows[rr]*EDIM + t];
        __syncthreads();
        if (t < RB) znl[t] = np_pairwise_sumsq(&zl[t][0]);
        __syncthreads();

        float acc[RB][4];
        #pragma unroll
        for (int rr = 0; rr < RB; ++rr)
            #pragma unroll
            for (int c = 0; c < 4; ++c) acc[rr][c] = 0.f;
        const float* eb = ET + slice*1024 + t;
        #pragma unroll 1
        for (int d = 0; d < 256; ++d) {           // sequential ascending d (np order)
            const float* ep = eb + (size_t)d * NE;
            float v0 = ep[0], v1 = ep[256], v2 = ep[512], v3 = ep[768];
            #pragma unroll
            for (int rr = 0; rr < RB; ++rr) {
                float zd = zl[rr][d];
                acc[rr][0] = fmaf(zd, v0, acc[rr][0]);
                acc[rr][1] = fmaf(zd, v1, acc[rr][1]);
                acc[rr][2] = fmaf(zd, v2, acc[rr][2]);
                acc[rr][3] = fmaf(zd, v3, acc[rr][3]);
            }
        }
        #pragma unroll 1
        for (int rr = 0; rr < RB; ++rr) {
            int row = rows[rr];
            float zn = znl[rr];
            float bv = FLT_MAX; int bi = 0x7fffffff;
            {
#pragma clang fp contract(off)
                #pragma unroll
                for (int c = 0; c < 4; ++c) {
                    int k = slice*1024 + c*256 + t;
                    float S  = zn + enorm[k];
                    float tw = 2.0f * acc[rr][c];
                    float sc = S - tw;
                    if (sc < bv || (sc == bv && k < bi)) { bv = sc; bi = k; }
                }
            }
            sv[t] = bv; si[t] = bi;
            __syncthreads();
            for (int st = 128; st > 0; st >>= 1) {
                if (t < st) {
                    float ov = sv[t+st]; int oi = si[t+st];
                    if (ov < sv[t] || (ov == sv[t] && oi < si[t])) { sv[t] = ov; si[t] = oi; }
                }
                __syncthreads();
            }
            if (t == 0) {
                uint64 pk = ((uint64)float_key(sv[0]) << 32) | (uint32)si[0];
                atomicMin(packed + row, pk);
            }
            __syncthreads();
        }
    }
}

// tail A: apply phase-B idx fix, write z_q_st + loss partial, histogram idx.
__global__ void k_taila(const float* __restrict__ Z, const float* __restrict__ E,
                        int* __restrict__ idxint, const uint64* __restrict__ packed,
                        float* __restrict__ out0, float* __restrict__ out_idx_f,
                        int* __restrict__ hist, float* __restrict__ lossp) {
    __shared__ float wsum[4];
    int t = threadIdx.x;
    int w = t >> 6, lane = t & 63;
    int row = blockIdx.x * 4 + w;
    int idx = idxint[row];
    uint64 pk = packed[row];
    if (pk != 0xFFFFFFFFFFFFFFFFull) {          // flagged: exact rescan result
        idx = (int)(uint32)(pk & 0xffffffffu);
        if (lane == 0) { out_idx_f[row] = (float)idx; idxint[row] = idx; }
    }
    float4 z4 = ((const float4*)Z)[(size_t)row * 64 + lane];
    float4 e4 = ((const float4*)E)[(size_t)idx * 64 + lane];
    float4 d4; d4.x = e4.x - z4.x; d4.y = e4.y - z4.y; d4.z = e4.z - z4.z; d4.w = e4.w - z4.w;
    float4 o;  o.x = z4.x + d4.x;  o.y = z4.y + d4.y;  o.z = z4.z + d4.z;  o.w = z4.w + d4.w;
    ((float4*)out0)[(size_t)row * 64 + lane] = o;
    float q2 = d4.x*d4.x + d4.y*d4.y + d4.z*d4.z + d4.w*d4.w;
    #pragma unroll
    for (int off = 32; off > 0; off >>= 1) q2 += __shfl_down(q2, off, 64);
    if (lane == 0) { wsum[w] = q2; atomicAdd(&hist[idx], 1); }
    __syncthreads();
    if (t == 0) lossp[blockIdx.x] = wsum[0] + wsum[1] + wsum[2] + wsum[3];
}

// exclusive prefix-scan of hist[8192] -> offs and cursor (one block)
__global__ void k_scan(const int* __restrict__ hist,
                       int* __restrict__ cursor, int* __restrict__ offs) {
    __shared__ int part[256];
    int t = threadIdx.x;
    int loc[32];
    int s = 0;
    #pragma unroll
    for (int j = 0; j < 32; ++j) { loc[j] = s; s += hist[t*32 + j]; }
    part[t] = s;
    __syncthreads();
    // Hillis-Steele inclusive scan over 256 partials
    #pragma unroll
    for (int off = 1; off < 256; off <<= 1) {
        int u = (t >= off) ? part[t - off] : 0;
        __syncthreads();
        part[t] += u;
        __syncthreads();
    }
    int base = part[t] - s;   // exclusive base for this thread's 32 codes
    #pragma unroll
    for (int j = 0; j < 32; ++j) {
        int o = base + loc[j];
        offs[t*32 + j] = o;
        cursor[t*32 + j] = o;
    }
}

// tail B: scatter row ids into per-code segments
__global__ void k_tailb(const int* __restrict__ idxint,
                        int* __restrict__ cursor, int* __restrict__ rowlist) {
    int g = blockIdx.x * 256 + threadIdx.x;
    int idx = idxint[g];
    int pos = atomicAdd(&cursor[idx], 1);
    rowlist[pos] = g;
}

// dw gather-sum per code + cl divide + loss reduce (block 0)
__global__ void k_dw(const float* __restrict__ Z, const int* __restrict__ hist,
                     const int* __restrict__ offs, const int* __restrict__ rowlist,
                     const float* __restrict__ lossp,
                     float* __restrict__ out3, float* __restrict__ out2) {
    __shared__ double red[256];
    int k = blockIdx.x;
    int t = threadIdx.x;
    int cnt = hist[k];
    int start = offs[k];
    float s0 = 0.f, s1 = 0.f;
    int j = 0;
    #pragma unroll 1
    for (; j + 1 < cnt; j += 2) {
        int ra = rowlist[start + j];
        int rb = rowlist[start + j + 1];
        s0 += Z[(size_t)ra * EDIM + t];
        s1 += Z[(size_t)rb * EDIM + t];
    }
    if (j < cnt) s0 += Z[(size_t)rowlist[start + j] * EDIM + t];
    float sum = s0 + s1;
    float cl = ((float)cnt + 1e-5f) / (32768.0f + 8192.0f * 1e-5f) * 32768.0f;
    out3[(size_t)k * EDIM + t] = sum / cl;
    if (k == 0) {
        double s = 0.0;
        #pragma unroll 1
        for (int p = t; p < 8192; p += 256) s += (double)lossp[p];
        red[t] = s;
        __syncthreads();
        #pragma unroll
        for (int st = 128; st > 0; st >>= 1) {
            if (t < st) red[t] += red[t + st];
            __syncthreads();
        }
        if (t == 0) out2[0] = 0.25f * (float)(red[0] / 8388608.0);
    }
}

extern "C" void kernel_launch(void* const* d_in, const int* in_sizes, int n_in,
                              void* d_out, int out_size, void* d_ws, size_t ws_size,
                              hipStream_t stream) {
    const float* Z = (const float*)d_in[0];   // [32768, 256]
    const float* E = (const float*)d_in[1];   // [8192, 256]
    float* out  = (float*)d_out;
    float* out0 = out;                         // z_q_st  (8388608)
    float* out1 = out + 8388608;               // idx as float (32768)
    float* out2 = out1 + 32768;                // loss (1)
    float* out3 = out2 + 1;                    // new_embeddings (2097152)

    char* ws = (char*)d_ws;
    unsigned short* Zcat = (unsigned short*)(ws + OFF_ZCAT);
    unsigned short* Ecat = (unsigned short*)(ws + OFF_ECAT);
    float*  ET      = (float*)(ws + OFF_ET);
    float*  enorm   = (float*)(ws + OFF_EN);
    float*  pv      = (float*)(ws + OFF_PV);
    int*    pi      = (int*)  (ws + OFF_PI);
    float*  pv2     = (float*)(ws + OFF_PV2);
    int*    idxint  = (int*)  (ws + OFF_IDX);
    int*    hist    = (int*)  (ws + OFF_BINS);
    uint64* packed  = (uint64*)(ws + OFF_PACKED);
    int*    flagcnt = (int*)  (ws + OFF_FLAGCNT);
    int*    flagged = (int*)  (ws + OFF_FLAGGED);
    float*  lossp   = (float*)(ws + OFF_PV);                 // after merge
    int*    rowlist = (int*)  (ws + OFF_PV + 32768);         // after merge
    int*    cursor  = (int*)  (ws + OFF_PV2);                // after merge
    int*    offs    = (int*)  (ws + OFF_PV2 + 32768);        // after merge

    k_prep   <<<5184,         256, 0, stream>>>(Z, E, Zcat, Ecat, ET, enorm,
                                                packed, hist, flagcnt);
    k_gemm   <<<256 * NTILES, 256, 0, stream>>>(Zcat, Ecat, enorm, pv, pi, pv2);
    k_merge  <<<512,          256, 0, stream>>>(pv, pi, pv2, out1, idxint, flagcnt, flagged);
    k_phaseB <<<2048,         256, 0, stream>>>(Z, ET, enorm, flagcnt, flagged, packed);
    k_taila  <<<N_ROWS / 4,   256, 0, stream>>>(Z, E, idxint, packed, out0, out1, hist, lossp);
    k_scan   <<<1,            256, 0, stream>>>(hist, cursor, offs);
    k_tailb  <<<N_ROWS / 256, 256, 0, stream>>>(idxint, cursor, rowlist);
    k_dw     <<<NE,           256, 0, stream>>>(Z, hist, offs, rowlist, lossp, out3, out2);
}